// Round 7
// baseline (326.438 us; speedup 1.0000x reference)
//
#include <hip/hip_runtime.h>
#include <hip/hip_bf16.h>

#define BB 4
#define NN 4096
#define DD 512
#define BND (BB*NN)   // 16384

typedef __attribute__((ext_vector_type(8))) short bf16x8;
typedef __attribute__((ext_vector_type(4))) float f32x4;

// ---------- bf16 helpers ----------
__device__ __forceinline__ float b2f(unsigned int u){
    union { unsigned int u; float f; } c; c.u = u << 16; return c.f;
}
__device__ __forceinline__ unsigned short f2b(float f){
    union { float f; unsigned int u; } c; c.f = f;
    unsigned int r = c.u + 0x7fffu + ((c.u >> 16) & 1u);   // RNE
    return (unsigned short)(r >> 16);
}
__device__ __forceinline__ unsigned int pack2(float lo, float hi){
    __hip_bfloat162 h = __float22bfloat162_rn(make_float2(lo, hi));
    return *reinterpret_cast<unsigned int*>(&h);
}
__device__ __forceinline__ void unpack8(uint4 v, float* o){
    o[0]=b2f(v.x & 0xffffu); o[1]=b2f(v.x >> 16);
    o[2]=b2f(v.y & 0xffffu); o[3]=b2f(v.y >> 16);
    o[4]=b2f(v.z & 0xffffu); o[5]=b2f(v.z >> 16);
    o[6]=b2f(v.w & 0xffffu); o[7]=b2f(v.w >> 16);
}

// async global->LDS, 16B/lane; lds dest is wave-uniform base + lane*16
__device__ __forceinline__ void gload16(const void* g, void* l){
    __builtin_amdgcn_global_load_lds(
        (const __attribute__((address_space(1))) unsigned int*)g,
        (__attribute__((address_space(3))) unsigned int*)l,
        16, 0, 0);
}

// ---- XOR-swizzled staging (rule #21: linear LDS dest, inverse-swizzled global src) ----
// LDS rows of 64 bf16 (8 chunks x 16B). Phys chunk c of row r holds logical chunk c^(r&7).
// stage 128 rows x 64 cols per block (4 waves):
__device__ __forceinline__ void stage128(const unsigned short* g, size_t gstride,
                                         unsigned short* lds, int w, int l){
    const int rr = l >> 3;                      // row within 8-group == r&7
    const int sc = ((l & 7) ^ rr) * 8;          // swizzled source col (elems)
    const unsigned short* src = g + (size_t)(w*32 + rr) * gstride + sc;
    unsigned short* dst = lds + w*32*64;
    #pragma unroll
    for (int blk = 0; blk < 4; ++blk)
        gload16(src + (size_t)blk*8*gstride, dst + blk*8*64);
}
// stage 64 rows x 64 cols per block (4 waves):
__device__ __forceinline__ void stage64(const unsigned short* g, size_t gstride,
                                        unsigned short* lds, int w, int l){
    const int rr = l >> 3;
    const int sc = ((l & 7) ^ rr) * 8;
    const unsigned short* src = g + (size_t)(w*16 + rr) * gstride + sc;
    unsigned short* dst = lds + w*16*64;
    #pragma unroll
    for (int blk = 0; blk < 2; ++blk)
        gload16(src + (size_t)blk*8*gstride, dst + blk*8*64);
}

// ---------- sin/cos table ----------
__global__ void k_sincos(float* __restrict__ sc){
    int t = blockIdx.x * 256 + threadIdx.x;
    if (t < NN){
        float idx = 1.5707963267948966f * ((float)(t + 1) / (float)NN);
        sc[t]      = sinf(idx);
        sc[NN + t] = cosf(idx);
    }
}

// ---------- fp32 -> bf16 bulk convert ----------
__global__ void k_cvt(const float* __restrict__ in, unsigned short* __restrict__ out, int n8){
    int t = blockIdx.x * 256 + threadIdx.x;
    if (t < n8){
        float4 a = reinterpret_cast<const float4*>(in)[t*2];
        float4 b = reinterpret_cast<const float4*>(in)[t*2+1];
        uint4 st;
        st.x = pack2(a.x, a.y); st.y = pack2(a.z, a.w);
        st.z = pack2(b.x, b.y); st.w = pack2(b.z, b.w);
        reinterpret_cast<uint4*>(out)[t] = st;
    }
}

// ---------- q,k,v projections. which 0: Q2=[sin*q|cos*q] row-major [BND][1024]
//            which 1: Ktsc=[sin*k; cos*k] transposed [1024][BND]
//            which 2: Vt transposed [512][BND]
__global__ __launch_bounds__(256) void k_qkv(
    const unsigned short* __restrict__ Xb,
    const unsigned short* __restrict__ Wqb,
    const unsigned short* __restrict__ Wkb,
    const unsigned short* __restrict__ Wvb,
    const float* __restrict__ sc,
    unsigned short* __restrict__ Q2,
    unsigned short* __restrict__ Ktsc,
    unsigned short* __restrict__ Vt)
{
    __shared__ __align__(16) unsigned short As[128*64];
    __shared__ __align__(16) unsigned short Bs[128*64];

    const int which = blockIdx.z;
    const unsigned short* W = (which == 0) ? Wqb : ((which == 1) ? Wkb : Wvb);

    const int tid = threadIdx.x;
    const int r0 = blockIdx.x * 128;
    const int c0 = blockIdx.y * 128;
    const int w  = tid >> 6, l = tid & 63;
    const int wr = (w >> 1) * 64, wc = (w & 1) * 64;
    const int lm = l & 15, lq = l >> 4;

    const unsigned short* aP = Xb + (size_t)r0 * DD;
    const unsigned short* bP = W  + (size_t)c0 * DD;

    f32x4 acc[4][4];
    #pragma unroll
    for (int i = 0; i < 4; ++i)
        #pragma unroll
        for (int j = 0; j < 4; ++j)
            #pragma unroll
            for (int q = 0; q < 4; ++q) acc[i][j][q] = 0.0f;

    for (int k0 = 0; k0 < DD; k0 += 64){
        __syncthreads();
        stage128(aP + k0, DD, As, w, l);
        stage128(bP + k0, DD, Bs, w, l);
        __syncthreads();
        bf16x8 af[4][2], bf[4][2];
        #pragma unroll
        for (int h = 0; h < 2; ++h){
            const int cs = ((h*4 + lq) ^ (lm & 7)) * 8;   // swizzled read chunk
            #pragma unroll
            for (int i = 0; i < 4; ++i){
                af[i][h] = *reinterpret_cast<const bf16x8*>(&As[(wr + i*16 + lm)*64 + cs]);
                bf[i][h] = *reinterpret_cast<const bf16x8*>(&Bs[(wc + i*16 + lm)*64 + cs]);
            }
        }
        #pragma unroll
        for (int h = 0; h < 2; ++h)
            #pragma unroll
            for (int i = 0; i < 4; ++i)
                #pragma unroll
                for (int j = 0; j < 4; ++j)
                    acc[i][j] = __builtin_amdgcn_mfma_f32_16x16x32_bf16(af[i][h], bf[j][h], acc[i][j], 0, 0, 0);
    }

    if (which == 0){
        #pragma unroll
        for (int i = 0; i < 4; ++i){
            #pragma unroll
            for (int q = 0; q < 4; ++q){
                int row = r0 + wr + i*16 + lq*4 + q;
                int n = row & (NN - 1);
                float sn = sc[n], cn = sc[NN + n];
                size_t base = (size_t)row * 1024 + c0 + wc + lm;
                #pragma unroll
                for (int j = 0; j < 4; ++j){
                    float v = fmaxf(acc[i][j][q], 0.0f);
                    Q2[base + j*16]       = f2b(sn * v);
                    Q2[base + 512 + j*16] = f2b(cn * v);
                }
            }
        }
    } else if (which == 1){
        #pragma unroll
        for (int i = 0; i < 4; ++i){
            int rb = r0 + wr + i*16 + lq*4;       // 4 consecutive global rows
            int n  = rb & (NN - 1);
            float4 s4 = *reinterpret_cast<const float4*>(sc + n);
            float4 c4 = *reinterpret_cast<const float4*>(sc + NN + n);
            #pragma unroll
            for (int j = 0; j < 4; ++j){
                int d = c0 + wc + j*16 + lm;
                float v0 = fmaxf(acc[i][j][0], 0.f), v1 = fmaxf(acc[i][j][1], 0.f);
                float v2 = fmaxf(acc[i][j][2], 0.f), v3 = fmaxf(acc[i][j][3], 0.f);
                uint2 stS, stC;
                stS.x = pack2(v0*s4.x, v1*s4.y); stS.y = pack2(v2*s4.z, v3*s4.w);
                stC.x = pack2(v0*c4.x, v1*c4.y); stC.y = pack2(v2*c4.z, v3*c4.w);
                *reinterpret_cast<uint2*>(Ktsc + (size_t)d * BND + rb)         = stS;
                *reinterpret_cast<uint2*>(Ktsc + (size_t)(512 + d) * BND + rb) = stC;
            }
        }
    } else {
        #pragma unroll
        for (int i = 0; i < 4; ++i){
            int rb = r0 + wr + i*16 + lq*4;
            #pragma unroll
            for (int j = 0; j < 4; ++j){
                int d = c0 + wc + j*16 + lm;
                uint2 st;
                st.x = pack2(acc[i][j][0], acc[i][j][1]);
                st.y = pack2(acc[i][j][2], acc[i][j][3]);
                *reinterpret_cast<uint2*>(Vt + (size_t)d * BND + rb) = st;
            }
        }
    }
}

// ---------- kvp[b][m][dp] += sum_n Ktsc[dp,n]*Vt[m,n]; split-8 over n ----------
__global__ __launch_bounds__(256) void k_kv(
    const unsigned short* __restrict__ Ktsc,
    const unsigned short* __restrict__ Vt,
    float* __restrict__ kvp)
{
    __shared__ __align__(16) unsigned short As[128*64];
    __shared__ __align__(16) unsigned short Bs[128*64];

    const int tid = threadIdx.x;
    const int dp0 = blockIdx.x * 128;
    const int m0  = blockIdx.y * 128;
    const int b   = blockIdx.z >> 3;
    const int sp  = blockIdx.z & 7;
    const int cb  = b * NN + sp * 512;
    const int w  = tid >> 6, l = tid & 63;
    const int wr = (w >> 1) * 64, wc = (w & 1) * 64;
    const int lm = l & 15, lq = l >> 4;

    const unsigned short* aP = Ktsc + (size_t)dp0 * BND + cb;
    const unsigned short* bP = Vt   + (size_t)m0  * BND + cb;

    f32x4 acc[4][4];
    #pragma unroll
    for (int i = 0; i < 4; ++i)
        #pragma unroll
        for (int j = 0; j < 4; ++j)
            #pragma unroll
            for (int q = 0; q < 4; ++q) acc[i][j][q] = 0.0f;

    for (int nb = 0; nb < 512; nb += 64){
        __syncthreads();
        stage128(aP + nb, BND, As, w, l);
        stage128(bP + nb, BND, Bs, w, l);
        __syncthreads();
        bf16x8 af[4][2], bf[4][2];
        #pragma unroll
        for (int h = 0; h < 2; ++h){
            const int cs = ((h*4 + lq) ^ (lm & 7)) * 8;
            #pragma unroll
            for (int i = 0; i < 4; ++i){
                af[i][h] = *reinterpret_cast<const bf16x8*>(&As[(wr + i*16 + lm)*64 + cs]);
                bf[i][h] = *reinterpret_cast<const bf16x8*>(&Bs[(wc + i*16 + lm)*64 + cs]);
            }
        }
        #pragma unroll
        for (int h = 0; h < 2; ++h)
            #pragma unroll
            for (int i = 0; i < 4; ++i)
                #pragma unroll
                for (int j = 0; j < 4; ++j)
                    acc[i][j] = __builtin_amdgcn_mfma_f32_16x16x32_bf16(af[i][h], bf[j][h], acc[i][j], 0, 0, 0);
    }

    // C rows = dp, cols = m. Write kvp[b][m][dp].
    #pragma unroll
    for (int i = 0; i < 4; ++i){
        #pragma unroll
        for (int q = 0; q < 4; ++q){
            int dp = dp0 + wr + i*16 + lq*4 + q;
            #pragma unroll
            for (int j = 0; j < 4; ++j){
                int m = m0 + wc + j*16 + lm;
                atomicAdd(kvp + ((size_t)b*512 + m) * 1024 + dp, acc[i][j][q]);
            }
        }
    }
}

// ---------- ksum[b][dp] = sum_n Ktsc[dp, b*NN+n] ----------
__global__ __launch_bounds__(256) void k_ksum(
    const unsigned short* __restrict__ Ktsc,
    float* __restrict__ ksum)
{
    int b = blockIdx.y;
    int dp = blockIdx.x * 4 + (threadIdx.x >> 6);
    int l = threadIdx.x & 63;
    const unsigned short* row = Ktsc + (size_t)dp * BND + b * NN;
    float ss = 0.f;
    for (int c0 = 0; c0 < NN; c0 += 512){
        float f[8];
        unpack8(*reinterpret_cast<const uint4*>(row + c0 + l*8), f);
        #pragma unroll
        for (int u = 0; u < 8; ++u) ss += f[u];
    }
    #pragma unroll
    for (int off = 32; off; off >>= 1) ss += __shfl_xor(ss, off);
    if (l == 0) ksum[b*1024 + dp] = ss;
}

// ---------- z[row] = 1/max(Q2[row,:].ksum[b,:], 1e-6) ----------
__global__ __launch_bounds__(256) void k_z(
    const unsigned short* __restrict__ Q2,
    const float* __restrict__ ksum,
    float* __restrict__ zden)
{
    int row  = blockIdx.x * 4 + (threadIdx.x >> 6);
    int lane = threadIdx.x & 63;
    int b = row >> 12;
    const unsigned short* qp = Q2 + (size_t)row * 1024 + lane * 16;
    float qf[16];
    unpack8(*reinterpret_cast<const uint4*>(qp), qf);
    unpack8(*reinterpret_cast<const uint4*>(qp + 8), qf + 8);
    const float* ks = ksum + (size_t)b*1024 + lane*16;
    float ps = 0.f;
    #pragma unroll
    for (int u = 0; u < 16; ++u) ps = fmaf(qf[u], ks[u], ps);
    #pragma unroll
    for (int off = 32; off; off >>= 1) ps += __shfl_xor(ps, off);
    if (lane == 0) zden[row] = 1.0f / fmaxf(ps, 1e-6f);
}

// ---------- out[n][m] = z * sum_dp Q2[n,dp]*kvb[b,m,dp]; 128x64 tiles ----------
__global__ __launch_bounds__(256) void k_out(
    const unsigned short* __restrict__ Q2,
    const unsigned short* __restrict__ kvb,
    const float* __restrict__ zden,
    float* __restrict__ Out)
{
    __shared__ __align__(16) unsigned short As[128*64];
    __shared__ __align__(16) unsigned short Bs[64*64];

    const int tid = threadIdx.x;
    const int r0 = blockIdx.x * 128;
    const int m0 = blockIdx.y * 64;
    const int b  = r0 >> 12;
    const int w  = tid >> 6, l = tid & 63;
    const int wr = (w >> 1) * 64, wc = (w & 1) * 32;
    const int lm = l & 15, lq = l >> 4;

    const unsigned short* aP = Q2 + (size_t)r0 * 1024;
    const unsigned short* bP = kvb + ((size_t)b*512 + m0) * 1024;

    f32x4 acc[4][2];
    #pragma unroll
    for (int i = 0; i < 4; ++i)
        #pragma unroll
        for (int j = 0; j < 2; ++j)
            #pragma unroll
            for (int q = 0; q < 4; ++q) acc[i][j][q] = 0.0f;

    for (int k0 = 0; k0 < 1024; k0 += 64){
        __syncthreads();
        stage128(aP + k0, 1024, As, w, l);
        stage64 (bP + k0, 1024, Bs, w, l);
        __syncthreads();
        bf16x8 af[4][2], bf[2][2];
        #pragma unroll
        for (int h = 0; h < 2; ++h){
            const int cs = ((h*4 + lq) ^ (lm & 7)) * 8;
            #pragma unroll
            for (int i = 0; i < 4; ++i)
                af[i][h] = *reinterpret_cast<const bf16x8*>(&As[(wr + i*16 + lm)*64 + cs]);
            #pragma unroll
            for (int j = 0; j < 2; ++j)
                bf[j][h] = *reinterpret_cast<const bf16x8*>(&Bs[(wc + j*16 + lm)*64 + cs]);
        }
        #pragma unroll
        for (int h = 0; h < 2; ++h)
            #pragma unroll
            for (int i = 0; i < 4; ++i)
                #pragma unroll
                for (int j = 0; j < 2; ++j)
                    acc[i][j] = __builtin_amdgcn_mfma_f32_16x16x32_bf16(af[i][h], bf[j][h], acc[i][j], 0, 0, 0);
    }

    #pragma unroll
    for (int i = 0; i < 4; ++i){
        #pragma unroll
        for (int q = 0; q < 4; ++q){
            int grow = r0 + wr + i*16 + lq*4 + q;
            int n = grow & (NN - 1);
            float z  = zden[grow];
            int hh = n >> 9;
            int ttb = (n & 511) * 8;
            #pragma unroll
            for (int j = 0; j < 2; ++j){
                int m = m0 + wc + j*16 + lm;
                int tt = ttb + (m >> 6);
                Out[((size_t)b*NN + tt) * DD + hh*64 + (m & 63)] = acc[i][j][q] * z;
            }
        }
    }
}

extern "C" void kernel_launch(void* const* d_in, const int* in_sizes, int n_in,
                              void* d_out, int out_size, void* d_ws, size_t ws_size,
                              hipStream_t stream)
{
    const float* X  = (const float*)d_in[0];
    const float* Wq = (const float*)d_in[1];
    const float* Wk = (const float*)d_in[2];
    const float* Wv = (const float*)d_in[3];
    float* Out = (float*)d_out;

    char* p = (char*)d_ws;
    float* sincos = (float*)p; p += (size_t)2*NN*sizeof(float);
    float* kvp    = (float*)p; p += (size_t)BB*512*1024*sizeof(float);   // 8 MB
    float* ksum   = (float*)p; p += (size_t)BB*1024*sizeof(float);
    float* zden   = (float*)p; p += (size_t)BND*sizeof(float);
    unsigned short* Xb   = (unsigned short*)p; p += (size_t)BND*DD*2;        // 16 MB
    unsigned short* Wqb  = (unsigned short*)p; p += (size_t)DD*DD*2;
    unsigned short* Wkb  = (unsigned short*)p; p += (size_t)DD*DD*2;
    unsigned short* Wvb  = (unsigned short*)p; p += (size_t)DD*DD*2;
    unsigned short* Q2   = (unsigned short*)p; p += (size_t)BND*1024*2;      // 32 MB
    unsigned short* Ktsc = (unsigned short*)p; p += (size_t)1024*BND*2;      // 32 MB
    unsigned short* Vt   = (unsigned short*)p; p += (size_t)512*BND*2;       // 16 MB
    unsigned short* kvb  = (unsigned short*)p; p += (size_t)BB*512*1024*2;   // 4 MB

    hipMemsetAsync(kvp, 0, (size_t)BB*512*1024*sizeof(float), stream);

    k_sincos<<<dim3(16), dim3(256), 0, stream>>>(sincos);
    k_cvt   <<<dim3(4096), dim3(256), 0, stream>>>(X,  Xb,  BND*DD/8);
    k_cvt   <<<dim3(128),  dim3(256), 0, stream>>>(Wq, Wqb, DD*DD/8);
    k_cvt   <<<dim3(128),  dim3(256), 0, stream>>>(Wk, Wkb, DD*DD/8);
    k_cvt   <<<dim3(128),  dim3(256), 0, stream>>>(Wv, Wvb, DD*DD/8);
    k_qkv   <<<dim3(BND/128, DD/128, 3), dim3(256), 0, stream>>>(Xb, Wqb, Wkb, Wvb, sincos, Q2, Ktsc, Vt);
    k_kv    <<<dim3(8, 4, 32), dim3(256), 0, stream>>>(Ktsc, Vt, kvp);
    k_ksum  <<<dim3(256, 4), dim3(256), 0, stream>>>(Ktsc, ksum);
    k_z     <<<dim3(BND/4), dim3(256), 0, stream>>>(Q2, ksum, zden);
    k_cvt   <<<dim3(1024), dim3(256), 0, stream>>>(kvp, kvb, BB*512*1024/8);
    k_out   <<<dim3(BND/128, 8), dim3(256), 0, stream>>>(Q2, kvb, zden, Out);
}

// Round 8
// 181.830 us; speedup vs baseline: 1.7953x; 1.7953x over previous
//
#include <hip/hip_runtime.h>
#include <hip/hip_bf16.h>

#define BB 4
#define NN 4096
#define DD 512
#define BND (BB*NN)   // 16384

typedef __attribute__((ext_vector_type(8))) short bf16x8;
typedef __attribute__((ext_vector_type(4))) float f32x4;

// ---------- bf16 helpers ----------
__device__ __forceinline__ float b2f(unsigned int u){
    union { unsigned int u; float f; } c; c.u = u << 16; return c.f;
}
__device__ __forceinline__ unsigned short f2b(float f){
    union { float f; unsigned int u; } c; c.f = f;
    unsigned int r = c.u + 0x7fffu + ((c.u >> 16) & 1u);   // RNE
    return (unsigned short)(r >> 16);
}
__device__ __forceinline__ unsigned int pack2(float lo, float hi){
    __hip_bfloat162 h = __float22bfloat162_rn(make_float2(lo, hi));
    return *reinterpret_cast<unsigned int*>(&h);
}
__device__ __forceinline__ void unpack8(uint4 v, float* o){
    o[0]=b2f(v.x & 0xffffu); o[1]=b2f(v.x >> 16);
    o[2]=b2f(v.y & 0xffffu); o[3]=b2f(v.y >> 16);
    o[4]=b2f(v.z & 0xffffu); o[5]=b2f(v.z >> 16);
    o[6]=b2f(v.w & 0xffffu); o[7]=b2f(v.w >> 16);
}

// async global->LDS, 16B/lane; lds dest is wave-uniform base + lane*16
__device__ __forceinline__ void gload16(const void* g, void* l){
    __builtin_amdgcn_global_load_lds(
        (const __attribute__((address_space(1))) unsigned int*)g,
        (__attribute__((address_space(3))) unsigned int*)l,
        16, 0, 0);
}

// ---- XOR-swizzled staging (linear LDS dest, inverse-swizzled global src) ----
// LDS rows of 64 bf16 (8 chunks x 16B). Phys chunk c of row r holds logical chunk c^(r&7).
__device__ __forceinline__ void stage128(const unsigned short* g, size_t gstride,
                                         unsigned short* lds, int w, int l){
    const int rr = l >> 3;                      // row within 8-group == r&7
    const int sc = ((l & 7) ^ rr) * 8;          // swizzled source col (elems)
    const unsigned short* src = g + (size_t)(w*32 + rr) * gstride + sc;
    unsigned short* dst = lds + w*32*64;
    #pragma unroll
    for (int blk = 0; blk < 4; ++blk)
        gload16(src + (size_t)blk*8*gstride, dst + blk*8*64);
}
__device__ __forceinline__ void stage64(const unsigned short* g, size_t gstride,
                                        unsigned short* lds, int w, int l){
    const int rr = l >> 3;
    const int sc = ((l & 7) ^ rr) * 8;
    const unsigned short* src = g + (size_t)(w*16 + rr) * gstride + sc;
    unsigned short* dst = lds + w*16*64;
    #pragma unroll
    for (int blk = 0; blk < 2; ++blk)
        gload16(src + (size_t)blk*8*gstride, dst + blk*8*64);
}

// ---------- sin/cos table ----------
__global__ void k_sincos(float* __restrict__ sc){
    int t = blockIdx.x * 256 + threadIdx.x;
    if (t < NN){
        float idx = 1.5707963267948966f * ((float)(t + 1) / (float)NN);
        sc[t]      = sinf(idx);
        sc[NN + t] = cosf(idx);
    }
}

// ---------- fp32 -> bf16 bulk convert ----------
__global__ void k_cvt(const float* __restrict__ in, unsigned short* __restrict__ out, int n8){
    int t = blockIdx.x * 256 + threadIdx.x;
    if (t < n8){
        float4 a = reinterpret_cast<const float4*>(in)[t*2];
        float4 b = reinterpret_cast<const float4*>(in)[t*2+1];
        uint4 st;
        st.x = pack2(a.x, a.y); st.y = pack2(a.z, a.w);
        st.z = pack2(b.x, b.y); st.w = pack2(b.z, b.w);
        reinterpret_cast<uint4*>(out)[t] = st;
    }
}

// ---------- q,k,v projections. which 0: Q2=[sin*q|cos*q] row-major [BND][1024]
//            which 1: Ktsc=[sin*k; cos*k] transposed [1024][BND]
//            which 2: Vt transposed [512][BND]
__global__ __launch_bounds__(256) void k_qkv(
    const unsigned short* __restrict__ Xb,
    const unsigned short* __restrict__ Wqb,
    const unsigned short* __restrict__ Wkb,
    const unsigned short* __restrict__ Wvb,
    const float* __restrict__ sc,
    unsigned short* __restrict__ Q2,
    unsigned short* __restrict__ Ktsc,
    unsigned short* __restrict__ Vt)
{
    __shared__ __align__(16) unsigned short As[128*64];
    __shared__ __align__(16) unsigned short Bs[128*64];

    const int which = blockIdx.z;
    const unsigned short* W = (which == 0) ? Wqb : ((which == 1) ? Wkb : Wvb);

    const int tid = threadIdx.x;
    const int r0 = blockIdx.x * 128;
    const int c0 = blockIdx.y * 128;
    const int w  = tid >> 6, l = tid & 63;
    const int wr = (w >> 1) * 64, wc = (w & 1) * 64;
    const int lm = l & 15, lq = l >> 4;

    const unsigned short* aP = Xb + (size_t)r0 * DD;
    const unsigned short* bP = W  + (size_t)c0 * DD;

    f32x4 acc[4][4];
    #pragma unroll
    for (int i = 0; i < 4; ++i)
        #pragma unroll
        for (int j = 0; j < 4; ++j)
            #pragma unroll
            for (int q = 0; q < 4; ++q) acc[i][j][q] = 0.0f;

    for (int k0 = 0; k0 < DD; k0 += 64){
        __syncthreads();
        stage128(aP + k0, DD, As, w, l);
        stage128(bP + k0, DD, Bs, w, l);
        __syncthreads();
        bf16x8 af[4][2], bf[4][2];
        #pragma unroll
        for (int h = 0; h < 2; ++h){
            const int cs = ((h*4 + lq) ^ (lm & 7)) * 8;   // swizzled read chunk
            #pragma unroll
            for (int i = 0; i < 4; ++i){
                af[i][h] = *reinterpret_cast<const bf16x8*>(&As[(wr + i*16 + lm)*64 + cs]);
                bf[i][h] = *reinterpret_cast<const bf16x8*>(&Bs[(wc + i*16 + lm)*64 + cs]);
            }
        }
        #pragma unroll
        for (int h = 0; h < 2; ++h)
            #pragma unroll
            for (int i = 0; i < 4; ++i)
                #pragma unroll
                for (int j = 0; j < 4; ++j)
                    acc[i][j] = __builtin_amdgcn_mfma_f32_16x16x32_bf16(af[i][h], bf[j][h], acc[i][j], 0, 0, 0);
    }

    if (which == 0){
        #pragma unroll
        for (int i = 0; i < 4; ++i){
            #pragma unroll
            for (int q = 0; q < 4; ++q){
                int row = r0 + wr + i*16 + lq*4 + q;
                int n = row & (NN - 1);
                float sn = sc[n], cn = sc[NN + n];
                size_t base = (size_t)row * 1024 + c0 + wc + lm;
                #pragma unroll
                for (int j = 0; j < 4; ++j){
                    float v = fmaxf(acc[i][j][q], 0.0f);
                    Q2[base + j*16]       = f2b(sn * v);
                    Q2[base + 512 + j*16] = f2b(cn * v);
                }
            }
        }
    } else if (which == 1){
        #pragma unroll
        for (int i = 0; i < 4; ++i){
            int rb = r0 + wr + i*16 + lq*4;       // 4 consecutive global rows
            int n  = rb & (NN - 1);
            float4 s4 = *reinterpret_cast<const float4*>(sc + n);
            float4 c4 = *reinterpret_cast<const float4*>(sc + NN + n);
            #pragma unroll
            for (int j = 0; j < 4; ++j){
                int d = c0 + wc + j*16 + lm;
                float v0 = fmaxf(acc[i][j][0], 0.f), v1 = fmaxf(acc[i][j][1], 0.f);
                float v2 = fmaxf(acc[i][j][2], 0.f), v3 = fmaxf(acc[i][j][3], 0.f);
                uint2 stS, stC;
                stS.x = pack2(v0*s4.x, v1*s4.y); stS.y = pack2(v2*s4.z, v3*s4.w);
                stC.x = pack2(v0*c4.x, v1*c4.y); stC.y = pack2(v2*c4.z, v3*c4.w);
                *reinterpret_cast<uint2*>(Ktsc + (size_t)d * BND + rb)         = stS;
                *reinterpret_cast<uint2*>(Ktsc + (size_t)(512 + d) * BND + rb) = stC;
            }
        }
    } else {
        #pragma unroll
        for (int i = 0; i < 4; ++i){
            int rb = r0 + wr + i*16 + lq*4;
            #pragma unroll
            for (int j = 0; j < 4; ++j){
                int d = c0 + wc + j*16 + lm;
                uint2 st;
                st.x = pack2(acc[i][j][0], acc[i][j][1]);
                st.y = pack2(acc[i][j][2], acc[i][j][3]);
                *reinterpret_cast<uint2*>(Vt + (size_t)d * BND + rb) = st;
            }
        }
    }
}

// ---------- kvp[b][m][dp] += sum_n Vt[m,n]*Ktsc[dp,n]; split-8 over n ----------
// A = Vt rows (m) -> C rows; B = Ktsc rows (dp) -> C cols; lane-contiguous dp => coalesced atomics.
__global__ __launch_bounds__(256) void k_kv(
    const unsigned short* __restrict__ Vt,
    const unsigned short* __restrict__ Ktsc,
    float* __restrict__ kvp)
{
    __shared__ __align__(16) unsigned short As[128*64];
    __shared__ __align__(16) unsigned short Bs[128*64];

    const int tid = threadIdx.x;
    const int m0  = blockIdx.x * 128;
    const int b   = blockIdx.z >> 3;
    const int sp  = blockIdx.z & 7;
    const int dp0 = ((blockIdx.y + sp) & 7) * 128;   // stagger: concurrent sp write different stripes
    const int cb  = b * NN + sp * 512;
    const int w  = tid >> 6, l = tid & 63;
    const int wr = (w >> 1) * 64, wc = (w & 1) * 64;
    const int lm = l & 15, lq = l >> 4;

    const unsigned short* aP = Vt   + (size_t)m0  * BND + cb;
    const unsigned short* bP = Ktsc + (size_t)dp0 * BND + cb;

    f32x4 acc[4][4];
    #pragma unroll
    for (int i = 0; i < 4; ++i)
        #pragma unroll
        for (int j = 0; j < 4; ++j)
            #pragma unroll
            for (int q = 0; q < 4; ++q) acc[i][j][q] = 0.0f;

    for (int nb = 0; nb < 512; nb += 64){
        __syncthreads();
        stage128(aP + nb, BND, As, w, l);
        stage128(bP + nb, BND, Bs, w, l);
        __syncthreads();
        bf16x8 af[4][2], bf[4][2];
        #pragma unroll
        for (int h = 0; h < 2; ++h){
            const int cs = ((h*4 + lq) ^ (lm & 7)) * 8;
            #pragma unroll
            for (int i = 0; i < 4; ++i){
                af[i][h] = *reinterpret_cast<const bf16x8*>(&As[(wr + i*16 + lm)*64 + cs]);
                bf[i][h] = *reinterpret_cast<const bf16x8*>(&Bs[(wc + i*16 + lm)*64 + cs]);
            }
        }
        #pragma unroll
        for (int h = 0; h < 2; ++h)
            #pragma unroll
            for (int i = 0; i < 4; ++i)
                #pragma unroll
                for (int j = 0; j < 4; ++j)
                    acc[i][j] = __builtin_amdgcn_mfma_f32_16x16x32_bf16(af[i][h], bf[j][h], acc[i][j], 0, 0, 0);
    }

    // C rows = m, cols = dp. kvp[b][m][dp], dp lane-contiguous.
    #pragma unroll
    for (int i = 0; i < 4; ++i){
        #pragma unroll
        for (int q = 0; q < 4; ++q){
            int m = m0 + wr + i*16 + lq*4 + q;
            float* rowp = kvp + ((size_t)b*512 + m) * 1024;
            #pragma unroll
            for (int j = 0; j < 4; ++j){
                int dp = dp0 + wc + j*16 + lm;
                atomicAdd(rowp + dp, acc[i][j][q]);
            }
        }
    }
}

// ---------- ksum[b][dp] = sum_n Ktsc[dp, b*NN+n] ----------
__global__ __launch_bounds__(256) void k_ksum(
    const unsigned short* __restrict__ Ktsc,
    float* __restrict__ ksum)
{
    int b = blockIdx.y;
    int dp = blockIdx.x * 4 + (threadIdx.x >> 6);
    int l = threadIdx.x & 63;
    const unsigned short* row = Ktsc + (size_t)dp * BND + b * NN;
    float ss = 0.f;
    for (int c0 = 0; c0 < NN; c0 += 512){
        float f[8];
        unpack8(*reinterpret_cast<const uint4*>(row + c0 + l*8), f);
        #pragma unroll
        for (int u = 0; u < 8; ++u) ss += f[u];
    }
    #pragma unroll
    for (int off = 32; off; off >>= 1) ss += __shfl_xor(ss, off);
    if (l == 0) ksum[b*1024 + dp] = ss;
}

// ---------- z[row] = 1/max(Q2[row,:].ksum[b,:], 1e-6) ----------
__global__ __launch_bounds__(256) void k_z(
    const unsigned short* __restrict__ Q2,
    const float* __restrict__ ksum,
    float* __restrict__ zden)
{
    int row  = blockIdx.x * 4 + (threadIdx.x >> 6);
    int lane = threadIdx.x & 63;
    int b = row >> 12;
    const unsigned short* qp = Q2 + (size_t)row * 1024 + lane * 16;
    float qf[16];
    unpack8(*reinterpret_cast<const uint4*>(qp), qf);
    unpack8(*reinterpret_cast<const uint4*>(qp + 8), qf + 8);
    const float* ks = ksum + (size_t)b*1024 + lane*16;
    float ps = 0.f;
    #pragma unroll
    for (int u = 0; u < 16; ++u) ps = fmaf(qf[u], ks[u], ps);
    #pragma unroll
    for (int off = 32; off; off >>= 1) ps += __shfl_xor(ps, off);
    if (lane == 0) zden[row] = 1.0f / fmaxf(ps, 1e-6f);
}

// ---------- out[n][m] = z * sum_dp Q2[n,dp]*kvb[b,m,dp]; 128x64 tiles ----------
__global__ __launch_bounds__(256) void k_out(
    const unsigned short* __restrict__ Q2,
    const unsigned short* __restrict__ kvb,
    const float* __restrict__ zden,
    float* __restrict__ Out)
{
    __shared__ __align__(16) unsigned short As[128*64];
    __shared__ __align__(16) unsigned short Bs[64*64];

    const int tid = threadIdx.x;
    const int r0 = blockIdx.x * 128;
    const int m0 = blockIdx.y * 64;
    const int b  = r0 >> 12;
    const int w  = tid >> 6, l = tid & 63;
    const int wr = (w >> 1) * 64, wc = (w & 1) * 32;
    const int lm = l & 15, lq = l >> 4;

    const unsigned short* aP = Q2 + (size_t)r0 * 1024;
    const unsigned short* bP = kvb + ((size_t)b*512 + m0) * 1024;

    f32x4 acc[4][2];
    #pragma unroll
    for (int i = 0; i < 4; ++i)
        #pragma unroll
        for (int j = 0; j < 2; ++j)
            #pragma unroll
            for (int q = 0; q < 4; ++q) acc[i][j][q] = 0.0f;

    for (int k0 = 0; k0 < 1024; k0 += 64){
        __syncthreads();
        stage128(aP + k0, 1024, As, w, l);
        stage64 (bP + k0, 1024, Bs, w, l);
        __syncthreads();
        bf16x8 af[4][2], bf[2][2];
        #pragma unroll
        for (int h = 0; h < 2; ++h){
            const int cs = ((h*4 + lq) ^ (lm & 7)) * 8;
            #pragma unroll
            for (int i = 0; i < 4; ++i)
                af[i][h] = *reinterpret_cast<const bf16x8*>(&As[(wr + i*16 + lm)*64 + cs]);
            #pragma unroll
            for (int j = 0; j < 2; ++j)
                bf[j][h] = *reinterpret_cast<const bf16x8*>(&Bs[(wc + j*16 + lm)*64 + cs]);
        }
        #pragma unroll
        for (int h = 0; h < 2; ++h)
            #pragma unroll
            for (int i = 0; i < 4; ++i)
                #pragma unroll
                for (int j = 0; j < 2; ++j)
                    acc[i][j] = __builtin_amdgcn_mfma_f32_16x16x32_bf16(af[i][h], bf[j][h], acc[i][j], 0, 0, 0);
    }

    #pragma unroll
    for (int i = 0; i < 4; ++i){
        #pragma unroll
        for (int q = 0; q < 4; ++q){
            int grow = r0 + wr + i*16 + lq*4 + q;
            int n = grow & (NN - 1);
            float z  = zden[grow];
            int hh = n >> 9;
            int ttb = (n & 511) * 8;
            #pragma unroll
            for (int j = 0; j < 2; ++j){
                int m = m0 + wc + j*16 + lm;
                int tt = ttb + (m >> 6);
                Out[((size_t)b*NN + tt) * DD + hh*64 + (m & 63)] = acc[i][j][q] * z;
            }
        }
    }
}

extern "C" void kernel_launch(void* const* d_in, const int* in_sizes, int n_in,
                              void* d_out, int out_size, void* d_ws, size_t ws_size,
                              hipStream_t stream)
{
    const float* X  = (const float*)d_in[0];
    const float* Wq = (const float*)d_in[1];
    const float* Wk = (const float*)d_in[2];
    const float* Wv = (const float*)d_in[3];
    float* Out = (float*)d_out;

    char* p = (char*)d_ws;
    float* sincos = (float*)p; p += (size_t)2*NN*sizeof(float);
    float* kvp    = (float*)p; p += (size_t)BB*512*1024*sizeof(float);   // 8 MB
    float* ksum   = (float*)p; p += (size_t)BB*1024*sizeof(float);
    float* zden   = (float*)p; p += (size_t)BND*sizeof(float);
    unsigned short* Xb   = (unsigned short*)p; p += (size_t)BND*DD*2;        // 16 MB
    unsigned short* Wqb  = (unsigned short*)p; p += (size_t)DD*DD*2;
    unsigned short* Wkb  = (unsigned short*)p; p += (size_t)DD*DD*2;
    unsigned short* Wvb  = (unsigned short*)p; p += (size_t)DD*DD*2;
    unsigned short* Q2   = (unsigned short*)p; p += (size_t)BND*1024*2;      // 32 MB
    unsigned short* Ktsc = (unsigned short*)p; p += (size_t)1024*BND*2;      // 32 MB
    unsigned short* Vt   = (unsigned short*)p; p += (size_t)512*BND*2;       // 16 MB
    unsigned short* kvb  = (unsigned short*)p; p += (size_t)BB*512*1024*2;   // 4 MB

    hipMemsetAsync(kvp, 0, (size_t)BB*512*1024*sizeof(float), stream);

    k_sincos<<<dim3(16), dim3(256), 0, stream>>>(sincos);
    k_cvt   <<<dim3(4096), dim3(256), 0, stream>>>(X,  Xb,  BND*DD/8);
    k_cvt   <<<dim3(128),  dim3(256), 0, stream>>>(Wq, Wqb, DD*DD/8);
    k_cvt   <<<dim3(128),  dim3(256), 0, stream>>>(Wk, Wkb, DD*DD/8);
    k_cvt   <<<dim3(128),  dim3(256), 0, stream>>>(Wv, Wvb, DD*DD/8);
    k_qkv   <<<dim3(BND/128, DD/128, 3), dim3(256), 0, stream>>>(Xb, Wqb, Wkb, Wvb, sincos, Q2, Ktsc, Vt);
    k_kv    <<<dim3(4, 8, 32), dim3(256), 0, stream>>>(Vt, Ktsc, kvp);
    k_ksum  <<<dim3(256, 4), dim3(256), 0, stream>>>(Ktsc, ksum);
    k_z     <<<dim3(BND/4), dim3(256), 0, stream>>>(Q2, ksum, zden);
    k_cvt   <<<dim3(1024), dim3(256), 0, stream>>>(kvp, kvb, BB*512*1024/8);
    k_out   <<<dim3(BND/128, 8), dim3(256), 0, stream>>>(Q2, kvb, zden, Out);
}